// Round 1
// baseline (172.587 us; speedup 1.0000x reference)
//
#include <hip/hip_runtime.h>

typedef short bf16x8 __attribute__((ext_vector_type(8)));
typedef float f32x4 __attribute__((ext_vector_type(4)));
typedef unsigned short u16;
typedef u16 u16x8 __attribute__((ext_vector_type(8)));
typedef u16 u16x4 __attribute__((ext_vector_type(4)));

#define L_ 2048
#define D_ 512
#define H_ 8
#define DH_ 64
#define DIN 508

static __device__ __forceinline__ u16 f2b(float f){
  unsigned u = __builtin_bit_cast(unsigned, f);
  unsigned r = u + 0x7fffu + ((u >> 16) & 1u);   // round-to-nearest-even
  return (u16)(r >> 16);
}
static __device__ __forceinline__ float b2f(u16 u){
  unsigned x = ((unsigned)u) << 16;
  return __builtin_bit_cast(float, x);
}
#define MFMA16(a,b,c) __builtin_amdgcn_mfma_f32_16x16x32_bf16(a,b,c,0,0,0)

// ---------------------------------------------------------------------------
// Kernel 1: fused QKV projection.  C[i][n] = sum_k Xpad[i][k] * W[n][k]
// X: 4096x512 (padded cols 0,1,510,511 = 0), W: concat(Wq,Wk,Wv) rows = 1536.
// Q,K stored bf16 as [bh][l][dh]; V stored TRANSPOSED bf16 as [bh][dh][l].
// ---------------------------------------------------------------------------
__global__ __launch_bounds__(512) void proj_kernel(
    const float* __restrict__ inp, const float* __restrict__ Wq,
    const float* __restrict__ Wk, const float* __restrict__ Wv,
    u16* __restrict__ Qg, u16* __restrict__ Kg, u16* __restrict__ Vt)
{
  __shared__ u16 Xl[128*72];   // [128 rows][64 k + pad8], stride 144B = 36dw (≡4 mod 32: conflict-free)
  __shared__ u16 Wl[128*72];
  const int t = threadIdx.x;
  const int lane = t & 63, wid = t >> 6;
  const int wr = wid >> 2, wc = wid & 3;          // 2x4 wave grid -> 64x32 per wave
  const int i0 = blockIdx.x * 128;
  const int j0 = blockIdx.y * 128;
  const int mat = j0 >> 9;                        // 0:Q 1:K 2:V (BN=128 never crosses 512)
  const float* __restrict__ W = (mat==0) ? Wq : (mat==1) ? Wk : Wv;
  const int jbase = j0 & 511;
  const int srow = t >> 3, sc8 = (t & 7) * 8;

  f32x4 acc[4][2];
  #pragma unroll
  for (int a=0;a<4;++a){
    #pragma unroll
    for (int bq=0;bq<2;++bq){ f32x4 z = {0.f,0.f,0.f,0.f}; acc[a][bq] = z; }
  }

  for (int kt=0; kt<8; ++kt){
    const int k0 = kt*64;
    __syncthreads();
    #pragma unroll
    for (int it=0; it<2; ++it){
      const int r = srow + 64*it;
      // X tile (bf16-convert + zero-pad)
      u16x8 xb;
      const int gi = i0 + r;
      #pragma unroll
      for (int e=0;e<8;++e){
        const int k = k0 + sc8 + e;
        float v = (k>=2 && k<510) ? inp[gi*DIN + (k-2)] : 0.f;
        xb[e] = f2b(v);
      }
      *(u16x8*)&Xl[r*72 + sc8] = xb;
      // W tile
      const float* wp = W + (jbase + r)*D_ + k0 + sc8;
      u16x8 wb;
      #pragma unroll
      for (int e=0;e<8;++e) wb[e] = f2b(wp[e]);
      *(u16x8*)&Wl[r*72 + sc8] = wb;
    }
    __syncthreads();
    #pragma unroll
    for (int ks=0; ks<2; ++ks){
      const int ko = ks*32 + (lane>>4)*8;
      bf16x8 af[4], bfr[2];
      #pragma unroll
      for (int fm=0; fm<4; ++fm)
        af[fm] = *(const bf16x8*)&Xl[(wr*64 + fm*16 + (lane&15))*72 + ko];
      #pragma unroll
      for (int fn=0; fn<2; ++fn)
        bfr[fn] = *(const bf16x8*)&Wl[(wc*32 + fn*16 + (lane&15))*72 + ko];
      #pragma unroll
      for (int fm=0; fm<4; ++fm){
        #pragma unroll
        for (int fn=0; fn<2; ++fn)
          acc[fm][fn] = MFMA16(af[fm], bfr[fn], acc[fm][fn]);
      }
    }
  }
  // epilogue: D mapping col = lane&15, row = (lane>>4)*4 + r
  #pragma unroll
  for (int fm=0; fm<4; ++fm){
    const int ibase = i0 + wr*64 + fm*16 + (lane>>4)*4;
    const int b = ibase >> 11;
    const int li = ibase & (L_-1);
    #pragma unroll
    for (int fn=0; fn<2; ++fn){
      const int n = j0 + wc*32 + fn*16 + (lane&15);
      const int h = (n>>6) & 7;
      const int dh = n & 63;
      if (mat == 2){
        u16x4 pk;
        #pragma unroll
        for (int r=0;r<4;++r) pk[r] = f2b(acc[fm][fn][r]);
        *(u16x4*)&Vt[((size_t)(b*H_+h)*DH_ + dh)*L_ + li] = pk;   // contiguous in l
      } else {
        u16* dst = ((mat==0)? Qg : Kg) + ((size_t)(b*H_+h)*L_ + li)*DH_ + dh;
        #pragma unroll
        for (int r=0;r<4;++r) dst[(size_t)r*DH_] = f2b(acc[fm][fn][r]);
      }
    }
  }
}

// ---------------------------------------------------------------------------
// Kernel 2: attention. One block = 32 q-rows of one (b,h). 512 thr = 8 waves.
// Whole unnormalized P row-block kept in LDS as bf16 (32 x 2048), so softmax
// needs no recompute: S-phase -> rowsum -> write attn (coalesced) -> PV.
// ---------------------------------------------------------------------------
__global__ __launch_bounds__(512) void attn_kernel(
    const u16* __restrict__ Qg, const u16* __restrict__ Kg,
    const u16* __restrict__ Vt, float* __restrict__ attn, float* __restrict__ Og)
{
  __shared__ u16 P[32*2056];     // 131584 B, stride 4112B = 1028dw (≡4 mod 32)
  __shared__ u16 KV[128*72];     // K tiles [128][72]; reused as Vt tiles [64][136]
  __shared__ float rsp[8][32];
  __shared__ float inv_rs[32];

  const int t = threadIdx.x, lane = t & 63, wid = t >> 6;
  const int q0 = blockIdx.x * 32;
  const int bh = blockIdx.y;
  const u16* Qp = Qg + ((size_t)bh*L_ + q0)*DH_;
  const u16* Kp = Kg + (size_t)bh*L_*DH_;
  const u16* Vp = Vt + (size_t)bh*DH_*L_;

  // Q fragments hoisted to registers (shared across all waves' column slices)
  bf16x8 qf[2][2];
  #pragma unroll
  for (int qi=0;qi<2;++qi){
    #pragma unroll
    for (int ks=0;ks<2;++ks)
      qf[qi][ks] = *(const bf16x8*)&Qp[(size_t)(qi*16 + (lane&15))*DH_ + ks*32 + (lane>>4)*8];
  }

  f32x4 racc[2];
  { f32x4 z = {0.f,0.f,0.f,0.f}; racc[0]=z; racc[1]=z; }

  // ---- S phase: S = Q K^T * 1/8, P = exp(S) (no max-sub: |S| ~ N(0,1)) ----
  for (int kt=0; kt<16; ++kt){
    __syncthreads();
    #pragma unroll
    for (int it=0; it<2; ++it){
      const int r = 64*it + (t>>3), c8 = (t&7)*8;
      *(u16x8*)&KV[r*72 + c8] = *(const u16x8*)&Kp[(size_t)(kt*128 + r)*DH_ + c8];
    }
    __syncthreads();
    const int ko = (lane>>4)*8;
    const int mrow = wid*16 + (lane&15);          // this wave's 16 m-columns
    bf16x8 b0 = *(const bf16x8*)&KV[mrow*72 + ko];
    bf16x8 b1 = *(const bf16x8*)&KV[mrow*72 + 32 + ko];
    #pragma unroll
    for (int qi=0;qi<2;++qi){
      f32x4 s = {0.f,0.f,0.f,0.f};
      s = MFMA16(qf[qi][0], b0, s);
      s = MFMA16(qf[qi][1], b1, s);
      #pragma unroll
      for (int r=0;r<4;++r){
        const float ev = __expf(s[r]*0.125f);
        const u16 ub = f2b(ev);
        P[(qi*16 + (lane>>4)*4 + r)*2056 + kt*128 + wid*16 + (lane&15)] = ub;
        racc[qi][r] += b2f(ub);                   // sum of the bf16-rounded values
      }
    }
  }
  // ---- row sums: reduce across the 16 lanes of each fragment column group ----
  #pragma unroll
  for (int off=1; off<16; off<<=1){
    #pragma unroll
    for (int qi=0;qi<2;++qi){
      #pragma unroll
      for (int r=0;r<4;++r)
        racc[qi][r] += __shfl_xor(racc[qi][r], off);
    }
  }
  if ((lane&15)==0){
    const int g = lane>>4;
    #pragma unroll
    for (int qi=0;qi<2;++qi){
      #pragma unroll
      for (int r=0;r<4;++r)
        rsp[wid][qi*16 + g*4 + r] = racc[qi][r];
    }
  }
  __syncthreads();
  if (t < 32){
    float s = 0.f;
    #pragma unroll
    for (int w=0;w<8;++w) s += rsp[w][t];
    inv_rs[t] = 1.f/s;
  }
  __syncthreads();
  // ---- write attn = P * inv_rowsum (fully coalesced float4 stores) ----
  {
    float* ao = attn + ((size_t)bh*L_ + q0)*L_ + t*4;
    for (int r=0;r<32;++r){
      const u16x4 pv = *(const u16x4*)&P[r*2056 + t*4];
      const float inv = inv_rs[r];
      float4 o;
      o.x = b2f(pv[0])*inv; o.y = b2f(pv[1])*inv;
      o.z = b2f(pv[2])*inv; o.w = b2f(pv[3])*inv;
      *(float4*)&ao[(size_t)r*L_] = o;
    }
  }
  // ---- PV: O[q][d] = sum_m P[q][m] V[m][d], V^T staged -> b128 B-frags ----
  const int qi = wid>>2, d0 = (wid&3)*16;         // wave owns one 16x16 output frag
  f32x4 o0 = {0.f,0.f,0.f,0.f}, o1 = {0.f,0.f,0.f,0.f};
  for (int vt=0; vt<16; ++vt){
    __syncthreads();
    #pragma unroll
    for (int it=0; it<2; ++it){
      const int r = 32*it + (t>>4), cm = (t&15)*8;
      *(u16x8*)&KV[r*136 + cm] = *(const u16x8*)&Vp[(size_t)r*L_ + vt*128 + cm];
    }
    __syncthreads();
    #pragma unroll
    for (int ms=0; ms<4; ++ms){
      bf16x8 pa = *(const bf16x8*)&P[(qi*16 + (lane&15))*2056 + vt*128 + ms*32 + (lane>>4)*8];
      bf16x8 vb = *(const bf16x8*)&KV[(d0 + (lane&15))*136 + ms*32 + (lane>>4)*8];
      if (ms&1) o1 = MFMA16(pa, vb, o1); else o0 = MFMA16(pa, vb, o0);
    }
  }
  {
    const int b = bh>>3, h = bh&7;
    #pragma unroll
    for (int r=0;r<4;++r){
      const int qr = qi*16 + (lane>>4)*4 + r;
      Og[((size_t)(b*L_ + q0 + qr))*D_ + h*DH_ + d0 + (lane&15)] = (o0[r]+o1[r])*inv_rs[qr];
    }
  }
}

// ---------------------------------------------------------------------------
// Kernel 3: residual add + LayerNorm over d=512 + slice to 508 cols.
// ---------------------------------------------------------------------------
__global__ __launch_bounds__(256) void ln_kernel(
    const float* __restrict__ Og, const float* __restrict__ inp,
    const float* __restrict__ gamma, const float* __restrict__ beta,
    float* __restrict__ out0)
{
  const int row = blockIdx.x, t = threadIdx.x;
  const int lane = t & 63, wid = t >> 6;
  const int c2 = t + 256;
  const float x1 = (t >= 2) ? inp[(size_t)row*DIN + t-2] : 0.f;       // t<256<510
  const float x2 = (c2 < 510) ? inp[(size_t)row*DIN + c2-2] : 0.f;    // c2>=258>2
  const float y1 = Og[(size_t)row*D_ + t]  + x1;
  const float y2 = Og[(size_t)row*D_ + c2] + x2;
  float s = y1 + y2, ss = y1*y1 + y2*y2;
  #pragma unroll
  for (int off=1; off<64; off<<=1){
    s  += __shfl_xor(s,  off);
    ss += __shfl_xor(ss, off);
  }
  __shared__ float red[4][2];
  if (lane == 0){ red[wid][0] = s; red[wid][1] = ss; }
  __syncthreads();
  s  = red[0][0]+red[1][0]+red[2][0]+red[3][0];
  ss = red[0][1]+red[1][1]+red[2][1]+red[3][1];
  const float mu   = s * (1.f/512.f);
  const float var  = ss * (1.f/512.f) - mu*mu;
  const float rstd = rsqrtf(var + 1e-6f);
  const float z1 = (y1 - mu)*rstd*gamma[t]  + beta[t];
  const float z2 = (y2 - mu)*rstd*gamma[c2] + beta[c2];
  if (t >= 2)   out0[(size_t)row*DIN + t-2]  = z1;
  if (c2 < 510) out0[(size_t)row*DIN + c2-2] = z2;
}

// ---------------------------------------------------------------------------
extern "C" void kernel_launch(void* const* d_in, const int* in_sizes, int n_in,
                              void* d_out, int out_size, void* d_ws, size_t ws_size,
                              hipStream_t stream) {
  const float* inp   = (const float*)d_in[0];
  const float* Wq    = (const float*)d_in[1];
  const float* Wk    = (const float*)d_in[2];
  const float* Wv    = (const float*)d_in[3];
  const float* gamma = (const float*)d_in[4];
  const float* beta  = (const float*)d_in[5];

  char* ws = (char*)d_ws;
  u16*   Qg = (u16*)(ws);                        // 2*8*2048*64 bf16 = 4 MB
  u16*   Kg = (u16*)(ws + 4194304);              // 4 MB
  u16*   Vt = (u16*)(ws + 8388608);              // 4 MB, transposed [bh][dh][l]
  float* Og = (float*)(ws + 12582912);           // 4096*512 f32 = 8 MB

  float* out0 = (float*)d_out;                   // (2,2048,508)
  float* attn = out0 + 2080768;                  // (2,8,2048,2048)

  proj_kernel<<<dim3(32,12), 512, 0, stream>>>(inp, Wq, Wk, Wv, Qg, Kg, Vt);
  attn_kernel<<<dim3(64,16), 512, 0, stream>>>(Qg, Kg, Vt, attn, Og);
  ln_kernel<<<4096, 256, 0, stream>>>(Og, inp, gamma, beta, out0);
}

// Round 2
// 129.335 us; speedup vs baseline: 1.3344x; 1.3344x over previous
//
#include <hip/hip_runtime.h>

typedef short bf16x8 __attribute__((ext_vector_type(8)));
typedef float f32x4 __attribute__((ext_vector_type(4)));
typedef unsigned short u16;
typedef u16 u16x8 __attribute__((ext_vector_type(8)));
typedef u16 u16x4 __attribute__((ext_vector_type(4)));

#define L_ 2048
#define D_ 512
#define H_ 8
#define DH_ 64
#define DIN 508

static __device__ __forceinline__ u16 f2b(float f){
  unsigned u = __builtin_bit_cast(unsigned, f);
  unsigned r = u + 0x7fffu + ((u >> 16) & 1u);   // round-to-nearest-even
  return (u16)(r >> 16);
}
static __device__ __forceinline__ float b2f(u16 u){
  unsigned x = ((unsigned)u) << 16;
  return __builtin_bit_cast(float, x);
}
#define MFMA16(a,b,c) __builtin_amdgcn_mfma_f32_16x16x32_bf16(a,b,c,0,0,0)

// ---------------------------------------------------------------------------
// Kernel 1: fused QKV projection.  C[i][n] = sum_k Xpad[i][k] * W[n][k]
// Q,K stored bf16 as [bh][l][dh]; V stored TRANSPOSED bf16 as [bh][dh][l].
// ---------------------------------------------------------------------------
__global__ __launch_bounds__(512) void proj_kernel(
    const float* __restrict__ inp, const float* __restrict__ Wq,
    const float* __restrict__ Wk, const float* __restrict__ Wv,
    u16* __restrict__ Qg, u16* __restrict__ Kg, u16* __restrict__ Vt)
{
  __shared__ u16 Xl[128*72];   // stride 72 u16 = 36dw (== 4 mod 32): conflict-free
  __shared__ u16 Wl[128*72];
  const int t = threadIdx.x;
  const int lane = t & 63, wid = t >> 6;
  const int wr = wid >> 2, wc = wid & 3;          // 2x4 wave grid -> 64x32 per wave
  const int i0 = blockIdx.x * 128;
  const int j0 = blockIdx.y * 128;
  const int mat = j0 >> 9;                        // 0:Q 1:K 2:V
  const float* __restrict__ W = (mat==0) ? Wq : (mat==1) ? Wk : Wv;
  const int jbase = j0 & 511;
  const int srow = t >> 3, sc8 = (t & 7) * 8;

  f32x4 acc[4][2];
  #pragma unroll
  for (int a=0;a<4;++a){
    #pragma unroll
    for (int bq=0;bq<2;++bq){ f32x4 z = {0.f,0.f,0.f,0.f}; acc[a][bq] = z; }
  }

  for (int kt=0; kt<8; ++kt){
    const int k0 = kt*64;
    __syncthreads();
    #pragma unroll
    for (int it=0; it<2; ++it){
      const int r = srow + 64*it;
      u16x8 xb;
      const int gi = i0 + r;
      #pragma unroll
      for (int e=0;e<8;++e){
        const int k = k0 + sc8 + e;
        float v = (k>=2 && k<510) ? inp[gi*DIN + (k-2)] : 0.f;
        xb[e] = f2b(v);
      }
      *(u16x8*)&Xl[r*72 + sc8] = xb;
      const float* wp = W + (jbase + r)*D_ + k0 + sc8;
      u16x8 wb;
      #pragma unroll
      for (int e=0;e<8;++e) wb[e] = f2b(wp[e]);
      *(u16x8*)&Wl[r*72 + sc8] = wb;
    }
    __syncthreads();
    #pragma unroll
    for (int ks=0; ks<2; ++ks){
      const int ko = ks*32 + (lane>>4)*8;
      bf16x8 af[4], bfr[2];
      #pragma unroll
      for (int fm=0; fm<4; ++fm)
        af[fm] = *(const bf16x8*)&Xl[(wr*64 + fm*16 + (lane&15))*72 + ko];
      #pragma unroll
      for (int fn=0; fn<2; ++fn)
        bfr[fn] = *(const bf16x8*)&Wl[(wc*32 + fn*16 + (lane&15))*72 + ko];
      #pragma unroll
      for (int fm=0; fm<4; ++fm){
        #pragma unroll
        for (int fn=0; fn<2; ++fn)
          acc[fm][fn] = MFMA16(af[fm], bfr[fn], acc[fm][fn]);
      }
    }
  }
  #pragma unroll
  for (int fm=0; fm<4; ++fm){
    const int ibase = i0 + wr*64 + fm*16 + (lane>>4)*4;
    const int b = ibase >> 11;
    const int li = ibase & (L_-1);
    #pragma unroll
    for (int fn=0; fn<2; ++fn){
      const int n = j0 + wc*32 + fn*16 + (lane&15);
      const int h = (n>>6) & 7;
      const int dh = n & 63;
      if (mat == 2){
        u16x4 pk;
        #pragma unroll
        for (int r=0;r<4;++r) pk[r] = f2b(acc[fm][fn][r]);
        *(u16x4*)&Vt[((size_t)(b*H_+h)*DH_ + dh)*L_ + li] = pk;   // contiguous in l
      } else {
        u16* dst = ((mat==0)? Qg : Kg) + ((size_t)(b*H_+h)*L_ + li)*DH_ + dh;
        #pragma unroll
        for (int r=0;r<4;++r) dst[(size_t)r*DH_] = f2b(acc[fm][fn][r]);
      }
    }
  }
}

// ---------------------------------------------------------------------------
// Kernel 2: attention, two-pass over K (recompute QK^T; no big P in LDS).
// Block = 32 q-rows of one (b,h), 512 thr = 8 waves. LDS ~45.7 KB -> 3 blk/CU.
// S^T form: mfma(K-frag, Q-frag) -> lane holds (m=(lane>>4)*4+r, q=lane&15):
//   pass A: fp32 rowsums of exp;  pass B: direct float4 attn stores + bf16
//   P-tile -> PV MFMA.
// ---------------------------------------------------------------------------
__global__ __launch_bounds__(512, 4) void attn_kernel(
    const u16* __restrict__ Qg, const u16* __restrict__ Kg,
    const u16* __restrict__ Vt, float* __restrict__ attn, float* __restrict__ Og)
{
  __shared__ u16 Kl[128*72];     // 18432 B
  __shared__ u16 Vl[64*136];     // 17408 B
  __shared__ u16 Pt[32*136];     //  8704 B
  __shared__ float rsp[8][32];
  __shared__ float inv_rs[32];

  const int t = threadIdx.x, lane = t & 63, wid = t >> 6;
  const int q0 = blockIdx.x * 32;
  const int bh = blockIdx.y;
  const u16* Qp = Qg + ((size_t)bh*L_ + q0)*DH_;
  const u16* Kp = Kg + (size_t)bh*L_*DH_;
  const u16* Vp = Vt + (size_t)bh*DH_*L_;

  // Q fragments: rows q = qi*16 + (lane&15), cols k = ks*32 + (lane>>4)*8
  bf16x8 qf[2][2];
  #pragma unroll
  for (int qi=0;qi<2;++qi){
    #pragma unroll
    for (int ks=0;ks<2;++ks)
      qf[qi][ks] = *(const bf16x8*)&Qp[(size_t)(qi*16 + (lane&15))*DH_ + ks*32 + (lane>>4)*8];
  }

  const int kr0 = t>>3, kc8 = (t&7)*8;     // K staging: rows kr0, kr0+64
  const int vr0 = t>>4, vcm = (t&15)*8;    // V staging: rows vr0, vr0+32
  const int g4 = (lane>>4)*8;
  const int mrow = wid*16 + (lane&15);     // this wave's K rows (m slice)

  // ---------------- pass A: row sums of exp(S) ----------------
  float racc0 = 0.f, racc1 = 0.f;
  u16x8 ka = *(const u16x8*)&Kp[(size_t)kr0*DH_ + kc8];
  u16x8 kb = *(const u16x8*)&Kp[(size_t)(64+kr0)*DH_ + kc8];
  for (int kt=0; kt<16; ++kt){
    __syncthreads();
    *(u16x8*)&Kl[kr0*72 + kc8] = ka;
    *(u16x8*)&Kl[(64+kr0)*72 + kc8] = kb;
    __syncthreads();
    if (kt < 15){
      ka = *(const u16x8*)&Kp[(size_t)((kt+1)*128 + kr0)*DH_ + kc8];
      kb = *(const u16x8*)&Kp[(size_t)((kt+1)*128 + 64 + kr0)*DH_ + kc8];
    }
    bf16x8 kf0 = *(const bf16x8*)&Kl[mrow*72 + g4];
    bf16x8 kf1 = *(const bf16x8*)&Kl[mrow*72 + 32 + g4];
    f32x4 s0 = {0.f,0.f,0.f,0.f}, s1 = {0.f,0.f,0.f,0.f};
    s0 = MFMA16(kf0, qf[0][0], s0); s0 = MFMA16(kf1, qf[0][1], s0);
    s1 = MFMA16(kf0, qf[1][0], s1); s1 = MFMA16(kf1, qf[1][1], s1);
    #pragma unroll
    for (int r=0;r<4;++r){
      racc0 += __expf(s0[r]*0.125f);
      racc1 += __expf(s1[r]*0.125f);
    }
  }
  racc0 += __shfl_xor(racc0, 16); racc0 += __shfl_xor(racc0, 32);
  racc1 += __shfl_xor(racc1, 16); racc1 += __shfl_xor(racc1, 32);
  if (lane < 16){ rsp[wid][lane] = racc0; rsp[wid][16+lane] = racc1; }
  __syncthreads();
  if (t < 32){
    float s = 0.f;
    #pragma unroll
    for (int w=0;w<8;++w) s += rsp[w][t];
    inv_rs[t] = 1.f/s;
  }
  __syncthreads();
  const float invq0 = inv_rs[lane&15];
  const float invq1 = inv_rs[16 + (lane&15)];

  // ---------------- pass B: attn stores + PV ----------------
  const int qpv = wid>>2, d0 = (wid&3)*16;       // PV: wave owns 16q x 16d frag
  f32x4 o0 = {0.f,0.f,0.f,0.f}, o1 = {0.f,0.f,0.f,0.f};
  float* arow0 = attn + ((size_t)bh*L_ + q0 + (lane&15))*L_ + wid*16 + (lane>>4)*4;
  float* arow1 = arow0 + (size_t)16*L_;

  ka = *(const u16x8*)&Kp[(size_t)kr0*DH_ + kc8];
  kb = *(const u16x8*)&Kp[(size_t)(64+kr0)*DH_ + kc8];
  u16x8 va = *(const u16x8*)&Vp[(size_t)vr0*L_ + vcm];
  u16x8 vb = *(const u16x8*)&Vp[(size_t)(32+vr0)*L_ + vcm];
  for (int kt=0; kt<16; ++kt){
    __syncthreads();                             // LDS free (prev PV done)
    *(u16x8*)&Kl[kr0*72 + kc8] = ka;
    *(u16x8*)&Kl[(64+kr0)*72 + kc8] = kb;
    *(u16x8*)&Vl[vr0*136 + vcm] = va;
    *(u16x8*)&Vl[(32+vr0)*136 + vcm] = vb;
    __syncthreads();
    if (kt < 15){
      ka = *(const u16x8*)&Kp[(size_t)((kt+1)*128 + kr0)*DH_ + kc8];
      kb = *(const u16x8*)&Kp[(size_t)((kt+1)*128 + 64 + kr0)*DH_ + kc8];
      va = *(const u16x8*)&Vp[(size_t)vr0*L_ + (kt+1)*128 + vcm];
      vb = *(const u16x8*)&Vp[(size_t)(32+vr0)*L_ + (kt+1)*128 + vcm];
    }
    bf16x8 kf0 = *(const bf16x8*)&Kl[mrow*72 + g4];
    bf16x8 kf1 = *(const bf16x8*)&Kl[mrow*72 + 32 + g4];
    f32x4 s0 = {0.f,0.f,0.f,0.f}, s1 = {0.f,0.f,0.f,0.f};
    s0 = MFMA16(kf0, qf[0][0], s0); s0 = MFMA16(kf1, qf[0][1], s0);
    s1 = MFMA16(kf0, qf[1][0], s1); s1 = MFMA16(kf1, qf[1][1], s1);
    float4 a0, a1; u16x4 p0, p1;
    float e;
    e = __expf(s0[0]*0.125f); a0.x = e*invq0; p0[0] = f2b(e);
    e = __expf(s0[1]*0.125f); a0.y = e*invq0; p0[1] = f2b(e);
    e = __expf(s0[2]*0.125f); a0.z = e*invq0; p0[2] = f2b(e);
    e = __expf(s0[3]*0.125f); a0.w = e*invq0; p0[3] = f2b(e);
    e = __expf(s1[0]*0.125f); a1.x = e*invq1; p1[0] = f2b(e);
    e = __expf(s1[1]*0.125f); a1.y = e*invq1; p1[1] = f2b(e);
    e = __expf(s1[2]*0.125f); a1.z = e*invq1; p1[2] = f2b(e);
    e = __expf(s1[3]*0.125f); a1.w = e*invq1; p1[3] = f2b(e);
    *(float4*)&arow0[kt*128] = a0;               // direct attn store (normalized)
    *(float4*)&arow1[kt*128] = a1;
    *(u16x4*)&Pt[(lane&15)*136 + wid*16 + (lane>>4)*4] = p0;
    *(u16x4*)&Pt[(16 + (lane&15))*136 + wid*16 + (lane>>4)*4] = p1;
    __syncthreads();                             // Pt ready
    #pragma unroll
    for (int ms=0; ms<4; ++ms){
      bf16x8 pa = *(const bf16x8*)&Pt[(qpv*16 + (lane&15))*136 + ms*32 + g4];
      bf16x8 vv = *(const bf16x8*)&Vl[(d0 + (lane&15))*136 + ms*32 + g4];
      if (ms&1) o1 = MFMA16(pa, vv, o1); else o0 = MFMA16(pa, vv, o0);
    }
  }
  {
    const int b = bh>>3, h = bh&7;
    #pragma unroll
    for (int r=0;r<4;++r){
      const int qr = qpv*16 + (lane>>4)*4 + r;
      Og[((size_t)(b*L_ + q0 + qr))*D_ + h*DH_ + d0 + (lane&15)] = (o0[r]+o1[r])*inv_rs[qr];
    }
  }
}

// ---------------------------------------------------------------------------
// Kernel 3: residual add + LayerNorm over d=512 + slice to 508 cols.
// ---------------------------------------------------------------------------
__global__ __launch_bounds__(256) void ln_kernel(
    const float* __restrict__ Og, const float* __restrict__ inp,
    const float* __restrict__ gamma, const float* __restrict__ beta,
    float* __restrict__ out0)
{
  const int row = blockIdx.x, t = threadIdx.x;
  const int lane = t & 63, wid = t >> 6;
  const int c2 = t + 256;
  const float x1 = (t >= 2) ? inp[(size_t)row*DIN + t-2] : 0.f;
  const float x2 = (c2 < 510) ? inp[(size_t)row*DIN + c2-2] : 0.f;
  const float y1 = Og[(size_t)row*D_ + t]  + x1;
  const float y2 = Og[(size_t)row*D_ + c2] + x2;
  float s = y1 + y2, ss = y1*y1 + y2*y2;
  #pragma unroll
  for (int off=1; off<64; off<<=1){
    s  += __shfl_xor(s,  off);
    ss += __shfl_xor(ss, off);
  }
  __shared__ float red[4][2];
  if (lane == 0){ red[wid][0] = s; red[wid][1] = ss; }
  __syncthreads();
  s  = red[0][0]+red[1][0]+red[2][0]+red[3][0];
  ss = red[0][1]+red[1][1]+red[2][1]+red[3][1];
  const float mu   = s * (1.f/512.f);
  const float var  = ss * (1.f/512.f) - mu*mu;
  const float rstd = rsqrtf(var + 1e-6f);
  const float z1 = (y1 - mu)*rstd*gamma[t]  + beta[t];
  const float z2 = (y2 - mu)*rstd*gamma[c2] + beta[c2];
  if (t >= 2)   out0[(size_t)row*DIN + t-2]  = z1;
  if (c2 < 510) out0[(size_t)row*DIN + c2-2] = z2;
}

// ---------------------------------------------------------------------------
extern "C" void kernel_launch(void* const* d_in, const int* in_sizes, int n_in,
                              void* d_out, int out_size, void* d_ws, size_t ws_size,
                              hipStream_t stream) {
  const float* inp   = (const float*)d_in[0];
  const float* Wq    = (const float*)d_in[1];
  const float* Wk    = (const float*)d_in[2];
  const float* Wv    = (const float*)d_in[3];
  const float* gamma = (const float*)d_in[4];
  const float* beta  = (const float*)d_in[5];

  char* ws = (char*)d_ws;
  u16*   Qg = (u16*)(ws);                        // 4 MB
  u16*   Kg = (u16*)(ws + 4194304);              // 4 MB
  u16*   Vt = (u16*)(ws + 8388608);              // 4 MB, transposed [bh][dh][l]
  float* Og = (float*)(ws + 12582912);           // 8 MB

  float* out0 = (float*)d_out;                   // (2,2048,508)
  float* attn = out0 + 2080768;                  // (2,8,2048,2048)

  proj_kernel<<<dim3(32,12), 512, 0, stream>>>(inp, Wq, Wk, Wv, Qg, Kg, Vt);
  attn_kernel<<<dim3(64,16), 512, 0, stream>>>(Qg, Kg, Vt, attn, Og);
  ln_kernel<<<4096, 256, 0, stream>>>(Og, inp, gamma, beta, out0);
}